// Round 4
// baseline (2761.382 us; speedup 1.0000x reference)
//
#include <hip/hip_runtime.h>
#include <hip/hip_bf16.h>
#include <hip/hip_fp8.h>
#include <math.h>

#define H 32
#define SCB 1024

__device__ __forceinline__ unsigned f2bf(float f) {  // f32 -> bf16 bits, RNE
  unsigned u = __float_as_uint(f);
  return (u + 0x7fffu + ((u >> 16) & 1u)) >> 16;
}
__device__ __forceinline__ float bflo(unsigned p) { return __uint_as_float(p << 16); }
__device__ __forceinline__ float bfhi(unsigned p) { return __uint_as_float(p & 0xffff0000u); }

// f32 -> OCP e4m3fn byte (RNE, saturating) via HIP type
__device__ __forceinline__ unsigned f2q(float f) {
  __hip_fp8_e4m3 q(f);
  return (unsigned)q.__x;
}
// OCP e4m3fn byte -> f32, branchless manual decode (~6 VALU)
__device__ __forceinline__ float q2f(unsigned b) {
  unsigned s = (b >> 7) & 1u, e = (b >> 3) & 15u, m = b & 7u;
  float vn = __uint_as_float((s << 31) | ((e + 120u) << 23) | (m << 20));
  float vs = __uint_as_float((s << 31) | 0x3f800000u) * ((float)(int)m * (1.0f / 512.0f));
  return (e == 0u) ? vs : vn;
}

// h = x@Wn+bn ; pk[n][c] = {e4m3(h), e4m3(h@lnw0+lnb0 - h)} packed in ushort
__global__ void k_encode(const float* __restrict__ x, const float* __restrict__ Wn,
                         const float* __restrict__ bn, const float* __restrict__ lnw0,
                         const float* __restrict__ lnb0, float* __restrict__ h,
                         unsigned short* __restrict__ pk, int n, int fnode) {
  __shared__ float sw[H * H];
  int tid = threadIdx.x;
  for (int i = tid; i < H * H; i += blockDim.x) sw[i] = lnw0[i];
  __syncthreads();
  int gid = blockIdx.x * blockDim.x + tid;
  int node = gid >> 5, c = gid & 31;
  if (node >= n) return;
  float acc = bn[c];
  for (int k = 0; k < fnode; ++k)
    acc = fmaf(x[node * fnode + k], Wn[k * H + c], acc);
  h[node * H + c] = acc;
  float t = lnb0[c];
#pragma unroll
  for (int k = 0; k < H; ++k)
    t = fmaf(__shfl(acc, k, 32), sw[k * H + c], t);
  pk[node * H + c] = (unsigned short)(f2q(acc) | (f2q(t - acc) << 8));
}

// W2[l] = We @ le_w[l]  ([2,H]) ; b2[l] = be @ le_w[l] + le_b[l]
__global__ void k_fold(const float* __restrict__ We, const float* __restrict__ be,
                       const float* __restrict__ lew, const float* __restrict__ leb,
                       float* __restrict__ W2, float* __restrict__ b2, int L) {
  int gid = blockIdx.x * blockDim.x + threadIdx.x;
  if (gid >= L * H) return;
  int l = gid >> 5, c = gid & 31;
  const float* lw = lew + (size_t)l * H * H;
  float a0 = 0.f, a1 = 0.f, bb = leb[l * H + c];
  for (int j = 0; j < H; ++j) {
    float w = lw[j * H + c];
    a0 = fmaf(We[j], w, a0);
    a1 = fmaf(We[H + j], w, a1);
    bb = fmaf(be[j], w, bb);
  }
  W2[l * 2 * H + c] = a0;
  W2[l * 2 * H + H + c] = a1;
  b2[l * H + c] = bb;
}

__global__ void k_hist(const int* __restrict__ dst, unsigned* __restrict__ cnt, int e) {
  int i = blockIdx.x * blockDim.x + threadIdx.x;
  if (i < e) atomicAdd(&cnt[dst[i]], 1u);
}

// two-level scan: per-block exclusive + block sums
__global__ void k_scan1(const unsigned* __restrict__ cnt, unsigned* __restrict__ out,
                        unsigned* __restrict__ bsum, int n) {
  __shared__ unsigned s[SCB];
  int i = blockIdx.x * SCB + threadIdx.x;
  unsigned v = (i < n) ? cnt[i] : 0u;
  s[threadIdx.x] = v;
  __syncthreads();
  for (int off = 1; off < SCB; off <<= 1) {
    unsigned u = (threadIdx.x >= off) ? s[threadIdx.x - off] : 0u;
    __syncthreads();
    s[threadIdx.x] += u;
    __syncthreads();
  }
  if (i < n) out[i] = s[threadIdx.x] - v;
  if (threadIdx.x == SCB - 1) bsum[blockIdx.x] = s[SCB - 1];
}

__global__ void k_scan2(const unsigned* __restrict__ bsum, unsigned* __restrict__ boff,
                        unsigned* __restrict__ total_out, int nb) {
  __shared__ unsigned s[SCB];
  unsigned v = ((int)threadIdx.x < nb) ? bsum[threadIdx.x] : 0u;
  s[threadIdx.x] = v;
  __syncthreads();
  for (int off = 1; off < SCB; off <<= 1) {
    unsigned u = (threadIdx.x >= off) ? s[threadIdx.x - off] : 0u;
    __syncthreads();
    s[threadIdx.x] += u;
    __syncthreads();
  }
  if ((int)threadIdx.x < nb) boff[threadIdx.x] = s[threadIdx.x] - v;
  if (threadIdx.x == SCB - 1) *total_out = s[SCB - 1];
}

__global__ void k_scan3(unsigned* __restrict__ row_ptr, const unsigned* __restrict__ boff,
                        unsigned* __restrict__ fill, int n) {
  int i = blockIdx.x * blockDim.x + threadIdx.x;
  if (i >= n) return;
  unsigned v = row_ptr[i] + boff[i >> 10];
  row_ptr[i] = v;
  fill[i] = v;
}

// rec = {src, bf16(attr0) | bf16(attr1)<<16}
__global__ void k_scatter(const int* __restrict__ src, const int* __restrict__ dst,
                          const float* __restrict__ ea, unsigned* __restrict__ fill,
                          uint2* __restrict__ recs, int e) {
  int i = blockIdx.x * blockDim.x + threadIdx.x;
  if (i >= e) return;
  int d = dst[i];
  unsigned pos = atomicAdd(&fill[d], 1u);
  float2 a = ((const float2*)ea)[i];
  recs[pos] = make_uint2((unsigned)src[i], f2bf(a.x) | (f2bf(a.y) << 16));
}

// per dst node (32 lanes): gather-accumulate fp8 messages (masked batches of 8),
// node update, then produce next layer's pk in the epilogue.
__global__ void __launch_bounds__(256) k_layer(
    const float* __restrict__ h, const unsigned short* __restrict__ pk,
    const unsigned* __restrict__ row_ptr, const uint2* __restrict__ recs,
    const float* __restrict__ W2l, const float* __restrict__ b2l,
    const float* __restrict__ luw, const float* __restrict__ lub,
    const float* __restrict__ lnw_next, const float* __restrict__ lnb_next,
    float* __restrict__ hout, unsigned short* __restrict__ pk_out, int n) {
  __shared__ float sw[2 * H * H];   // lu_w for this layer (8 KB)
  __shared__ float swn[H * H];      // ln_w for next layer (4 KB)
  int tid = threadIdx.x;
  for (int i = tid; i < 2 * H * H; i += 256) sw[i] = luw[i];
  if (lnw_next)
    for (int i = tid; i < H * H; i += 256) swn[i] = lnw_next[i];
  __syncthreads();
  int node = blockIdx.x * 8 + (tid >> 5);
  int c = tid & 31;
  if (node >= n) return;
  float w0 = W2l[c], w1 = W2l[H + c], bb = b2l[c];
  unsigned s0 = row_ptr[node], s1 = row_ptr[node + 1];
  float acc = 0.f;
  for (unsigned i = s0; i < s1; i += 8) {
    uint2 r[8];
    unsigned short p[8];
    float sc[8];
#pragma unroll
    for (int j = 0; j < 8; ++j) {
      unsigned idx = i + (unsigned)j;
      sc[j] = (idx < s1) ? 1.f : 0.f;
      idx = (idx < s1) ? idx : s0;
      r[j] = recs[idx];
    }
#pragma unroll
    for (int j = 0; j < 8; ++j) p[j] = pk[r[j].x * H + c];
#pragma unroll
    for (int j = 0; j < 8; ++j) {
      float ee = fmaf(bflo(r[j].y), w0, fmaf(bfhi(r[j].y), w1, bb));
      float xq = q2f((unsigned)p[j] & 255u);
      float uq = q2f((unsigned)p[j] >> 8);
      acc = fmaf(sc[j], fmaf(ee, uq, xq), acc);
    }
  }
  float hc = h[node * H + c];
  float o = lub[c];
#pragma unroll
  for (int k = 0; k < H; ++k) {
    float hk = __shfl(hc, k, 32);
    float ak = __shfl(acc, k, 32);
    o = fmaf(hk, sw[k * H + c], o);
    o = fmaf(ak, sw[(H + k) * H + c], o);
  }
  o = fmaxf(o, 0.f);
  hout[node * H + c] = o;
  if (pk_out) {
    float t = lnb_next[c];
#pragma unroll
    for (int k = 0; k < H; ++k)
      t = fmaf(__shfl(o, k, 32), swn[k * H + c], t);
    pk_out[node * H + c] = (unsigned short)(f2q(o) | (f2q(t - o) << 8));
  }
}

// classifier: sigmoid(relu(h@c1+b1)@c2 + b2)
__global__ void k_cls(const float* __restrict__ h, const float* __restrict__ c1w,
                      const float* __restrict__ c1b, const float* __restrict__ c2w,
                      const float* __restrict__ c2b, float* __restrict__ out, int n) {
  __shared__ float sw[H * H];
  int tid = threadIdx.x;
  for (int i = tid; i < H * H; i += blockDim.x) sw[i] = c1w[i];
  __syncthreads();
  int gid = blockIdx.x * blockDim.x + tid;
  int node = gid >> 5, c = gid & 31;
  if (node >= n) return;
  float hv = h[node * H + c];
  float z = c1b[c];
#pragma unroll
  for (int k = 0; k < H; ++k)
    z = fmaf(__shfl(hv, k, 32), sw[k * H + c], z);
  z = fmaxf(z, 0.f);
  float r = z * c2w[c];
#pragma unroll
  for (int m = 16; m >= 1; m >>= 1)
    r += __shfl_xor(r, m, 32);
  if (c == 0) out[node] = 1.f / (1.f + expf(-(r + c2b[0])));
}

extern "C" void kernel_launch(void* const* d_in, const int* in_sizes, int n_in,
                              void* d_out, int out_size, void* d_ws, size_t ws_size,
                              hipStream_t stream) {
  const float* x         = (const float*)d_in[0];
  const float* edge_attr = (const float*)d_in[1];
  const int*   edge_index= (const int*)d_in[2];
  const float* Wn        = (const float*)d_in[3];
  const float* bn        = (const float*)d_in[4];
  const float* We        = (const float*)d_in[5];
  const float* be        = (const float*)d_in[6];
  const float* ln_w      = (const float*)d_in[7];
  const float* ln_b      = (const float*)d_in[8];
  const float* le_w      = (const float*)d_in[9];
  const float* le_b      = (const float*)d_in[10];
  const float* lu_w      = (const float*)d_in[11];
  const float* lu_b      = (const float*)d_in[12];
  const float* c1w       = (const float*)d_in[13];
  const float* c1b       = (const float*)d_in[14];
  const float* c2w       = (const float*)d_in[15];
  const float* c2b       = (const float*)d_in[16];

  const int N_ = in_sizes[0] / 5;
  const int E_ = in_sizes[1] / 2;
  const int L_ = in_sizes[7] / (H * H);
  const int* src = edge_index;
  const int* dst = edge_index + E_;

  char* ws = (char*)d_ws;
  size_t off = 0;
  auto alloc = [&](size_t bytes) -> void* {
    void* p = ws + off;
    off = (off + bytes + 255) & ~(size_t)255;
    return p;
  };
  float*          hA      = (float*)alloc((size_t)N_ * H * 4);
  float*          hB      = (float*)alloc((size_t)N_ * H * 4);
  unsigned short* pkA     = (unsigned short*)alloc((size_t)N_ * H * 2);
  unsigned short* pkB     = (unsigned short*)alloc((size_t)N_ * H * 2);
  unsigned*       row_ptr = (unsigned*)alloc((size_t)(N_ + 1) * 4);
  unsigned*       fill    = (unsigned*)alloc((size_t)N_ * 4);
  uint2*          recs    = (uint2*)alloc((size_t)E_ * 8);
  float*          W2      = (float*)alloc((size_t)L_ * 2 * H * 4);
  float*          b2      = (float*)alloc((size_t)L_ * H * 4);
  unsigned*       bsum    = (unsigned*)alloc((size_t)SCB * 4);
  unsigned*       boff    = (unsigned*)alloc((size_t)SCB * 4);

  const int tb = 256;
  const int nb = (N_ + SCB - 1) / SCB;
  hipMemsetAsync(fill, 0, (size_t)N_ * 4, stream);
  k_encode<<<(N_ * 32 + tb - 1) / tb, tb, 0, stream>>>(x, Wn, bn, ln_w, ln_b, hA, pkA, N_, 5);
  k_fold<<<(L_ * H + 63) / 64, 64, 0, stream>>>(We, be, le_w, le_b, W2, b2, L_);
  k_hist<<<(E_ + tb - 1) / tb, tb, 0, stream>>>(dst, fill, E_);
  k_scan1<<<nb, SCB, 0, stream>>>(fill, row_ptr, bsum, N_);
  k_scan2<<<1, SCB, 0, stream>>>(bsum, boff, row_ptr + N_, nb);
  k_scan3<<<(N_ + tb - 1) / tb, tb, 0, stream>>>(row_ptr, boff, fill, N_);
  k_scatter<<<(E_ + tb - 1) / tb, tb, 0, stream>>>(src, dst, edge_attr, fill, recs, E_);

  float* hc = hA;  float* hn = hB;
  unsigned short* pc = pkA; unsigned short* pn = pkB;
  for (int l = 0; l < L_; ++l) {
    bool last = (l == L_ - 1);
    k_layer<<<(N_ + 7) / 8, 256, 0, stream>>>(
        hc, pc, row_ptr, recs, W2 + l * 2 * H, b2 + l * H,
        lu_w + (size_t)l * 2 * H * H, lu_b + (size_t)l * H,
        last ? nullptr : ln_w + (size_t)(l + 1) * H * H,
        last ? nullptr : ln_b + (size_t)(l + 1) * H,
        hn, last ? nullptr : pn, N_);
    float* tf = hc; hc = hn; hn = tf;
    unsigned short* tp = pc; pc = pn; pn = tp;
  }
  k_cls<<<(N_ * 32 + tb - 1) / tb, tb, 0, stream>>>(hc, c1w, c1b, c2w, c2b, (float*)d_out, N_);
}